// Round 4
// baseline (371.201 us; speedup 1.0000x reference)
//
#include <hip/hip_runtime.h>
#include <hip/hip_fp16.h>

#define D 64
#define RB 128            // rows per bin (7-bit local row)
#define NB_MAX 1024       // max bins (n_nodes <= 2^17)
#define NBLK1 512         // P1 blocks (2/CU, 8 waves/CU)
#define P1CAP 6272        // P1 LDS stage capacity (recs) = 50,176 B

typedef unsigned long long ull;
typedef unsigned short u16;

struct __align__(8) h4 { __half2 lo, hi; };   // 4 halves, single dwordx2 load

// rec = [ val:f32 (hi32) | localrow:bits17-23 | col:bits0-16 ]
__device__ __forceinline__ ull pack_rec(float v, int r, int c) {
    return ((ull)__float_as_uint(v) << 32) |
           (ull)(((unsigned)(r & (RB - 1)) << 17) | (unsigned)c);
}

// ---------------- fallback: atomic SpMM (guard path) ----------------
__global__ __launch_bounds__(256) void spmm_atomic_kernel(
    const float* __restrict__ x,
    const int*   __restrict__ edge_row,
    const int*   __restrict__ edge_col,
    const float* __restrict__ edge_val,
    float*       __restrict__ out,
    int n_edges)
{
    const int gtid = blockIdx.x * blockDim.x + threadIdx.x;
    const int wave = gtid >> 6;
    const int lane = threadIdx.x & 63;
    if (wave >= n_edges) return;
    const int   r = edge_row[wave];
    const int   c = edge_col[wave];
    const float v = edge_val[wave];
    atomicAdd(&out[(size_t)r * D + lane], v * x[(size_t)c * D + lane]);
}

// ---------------- RH: global histogram over key = (row<<3)|colslice ----------------
// 3.2 MB counter array is L2-resident; ~4 edges/key -> low atomic contention.
__global__ __launch_bounds__(256) void hist_kernel(
    const int* __restrict__ rows, const int* __restrict__ cols,
    int* __restrict__ hist, int n_edges)
{
    const int i = (blockIdx.x * 256 + threadIdx.x) * 4;
    if (i + 4 <= n_edges) {
        const int4 r = *(const int4*)(rows + i);
        const int4 c = *(const int4*)(cols + i);
        atomicAdd(&hist[(r.x << 3) | (c.x >> 14)], 1);
        atomicAdd(&hist[(r.y << 3) | (c.y >> 14)], 1);
        atomicAdd(&hist[(r.z << 3) | (c.z >> 14)], 1);
        atomicAdd(&hist[(r.w << 3) | (c.w >> 14)], 1);
    } else {
        for (int k = i; k < n_edges; ++k)
            atomicAdd(&hist[(rows[k] << 3) | (cols[k] >> 14)], 1);
    }
}

// ---------------- S1: per-4096-chunk exclusive scan + chunk sums ----------------
__global__ __launch_bounds__(1024) void scan1_kernel(
    const int* __restrict__ hist, int* __restrict__ keybase,
    int* __restrict__ sums, int nkeys)
{
    __shared__ int s[1024];
    const int t    = threadIdx.x;
    const int base = blockIdx.x * 4096 + t * 4;
    int4 v = make_int4(0, 0, 0, 0);
    if (base + 4 <= nkeys) {
        v = *(const int4*)(hist + base);
    } else {
        if (base + 0 < nkeys) v.x = hist[base + 0];
        if (base + 1 < nkeys) v.y = hist[base + 1];
        if (base + 2 < nkeys) v.z = hist[base + 2];
        if (base + 3 < nkeys) v.w = hist[base + 3];
    }
    const int sum = v.x + v.y + v.z + v.w;
    s[t] = sum;
    for (int off = 1; off < 1024; off <<= 1) {
        __syncthreads();
        const int w = (t >= off) ? s[t - off] : 0;
        __syncthreads();
        s[t] += w;
    }
    const int excl = s[t] - sum;
    if (t == 1023) sums[blockIdx.x] = s[t];
    int4 o;
    o.x = excl;
    o.y = o.x + v.x;
    o.z = o.y + v.y;
    o.w = o.z + v.z;
    if (base + 4 <= nkeys) {
        *(int4*)(keybase + base) = o;
    } else {
        if (base + 0 < nkeys) keybase[base + 0] = o.x;
        if (base + 1 < nkeys) keybase[base + 1] = o.y;
        if (base + 2 < nkeys) keybase[base + 2] = o.z;
        if (base + 3 < nkeys) keybase[base + 3] = o.w;
    }
}

// ---------------- S2: exclusive scan over chunk sums (n <= 256) ----------------
__global__ __launch_bounds__(256) void scan2_kernel(int* __restrict__ sums, int n)
{
    __shared__ int s[256];
    const int t = threadIdx.x;
    const int v = (t < n) ? sums[t] : 0;
    s[t] = v;
    for (int off = 1; off < 256; off <<= 1) {
        __syncthreads();
        const int w = (t >= off) ? s[t - off] : 0;
        __syncthreads();
        s[t] += w;
    }
    if (t < n) sums[t] = s[t] - v;
}

// ---------------- S3: add-back + sentinel ----------------
__global__ __launch_bounds__(256) void scan3_kernel(
    int* __restrict__ keybase, const int* __restrict__ sums,
    int nkeys, int n_edges)
{
    const int base = (blockIdx.x * 256 + threadIdx.x) * 4;
    const int add  = sums[blockIdx.x >> 2];   // 1024 elems/block, 4 blocks/chunk
    if (base + 4 <= nkeys) {
        int4 v = *(const int4*)(keybase + base);
        v.x += add; v.y += add; v.z += add; v.w += add;
        *(int4*)(keybase + base) = v;
    } else {
        for (int k = base; k < nkeys; ++k) keybase[k] += add;
    }
    if (blockIdx.x == 0 && threadIdx.x == 0) keybase[nkeys] = n_edges;
}

// ---------------- P1: per-block LDS counting sort + identity-coalesced writeout ----
__global__ __launch_bounds__(256) void p1_localsort_kernel(
    const int* __restrict__ rows, const int* __restrict__ cols,
    const float* __restrict__ vals,
    ull* __restrict__ staged, u16* __restrict__ counts, u16* __restrict__ startpos,
    int n_edges, int nb, int chunk)
{
    __shared__ ull stage[P1CAP];
    __shared__ int cnt[NB_MAX];
    __shared__ int s[256];
    const int t = threadIdx.x, blk = blockIdx.x;
    const int e0 = blk * chunk;
    const int e1 = min(e0 + chunk, n_edges);
    const int len = e1 - e0;

    for (int i = t; i < nb; i += 256) cnt[i] = 0;
    __syncthreads();

    // pass 1: histogram rows (int4)
    for (int i = e0 + t * 4; i < e1; i += 1024) {
        if (i + 4 <= e1) {
            const int4 r4 = *(const int4*)(rows + i);
            atomicAdd(&cnt[r4.x >> 7], 1);
            atomicAdd(&cnt[r4.y >> 7], 1);
            atomicAdd(&cnt[r4.z >> 7], 1);
            atomicAdd(&cnt[r4.w >> 7], 1);
        } else {
            for (int k = i; k < e1; ++k) atomicAdd(&cnt[rows[k] >> 7], 1);
        }
    }
    __syncthreads();

    // write counts + in-place exclusive scan of cnt
    int pre[4], sum = 0;
    const int base = t * 4;
    #pragma unroll
    for (int k = 0; k < 4; ++k) {
        const int idx = base + k;
        const int c = (idx < nb) ? cnt[idx] : 0;
        if (idx < nb) counts[(size_t)idx * NBLK1 + blk] = (u16)c;
        pre[k] = sum; sum += c;
    }
    s[t] = sum;
    for (int off = 1; off < 256; off <<= 1) {
        __syncthreads();
        const int w = (t >= off) ? s[t - off] : 0;
        __syncthreads();
        s[t] += w;
    }
    const int texcl = s[t] - sum;
    __syncthreads();
    #pragma unroll
    for (int k = 0; k < 4; ++k) {
        const int idx = base + k;
        if (idx < nb) {
            const int e = texcl + pre[k];
            cnt[idx] = e;                                   // becomes cursor
            startpos[(size_t)idx * NBLK1 + blk] = (u16)e;
        }
    }
    __syncthreads();

    // pass 2: scatter into LDS stage
    for (int i = e0 + t * 4; i < e1; i += 1024) {
        if (i + 4 <= e1) {
            const int4   r4 = *(const int4*)(rows + i);
            const int4   c4 = *(const int4*)(cols + i);
            const float4 v4 = *(const float4*)(vals + i);
            int p;
            p = atomicAdd(&cnt[r4.x >> 7], 1); stage[p] = pack_rec(v4.x, r4.x, c4.x);
            p = atomicAdd(&cnt[r4.y >> 7], 1); stage[p] = pack_rec(v4.y, r4.y, c4.y);
            p = atomicAdd(&cnt[r4.z >> 7], 1); stage[p] = pack_rec(v4.z, r4.z, c4.z);
            p = atomicAdd(&cnt[r4.w >> 7], 1); stage[p] = pack_rec(v4.w, r4.w, c4.w);
        } else {
            for (int k = i; k < e1; ++k) {
                const int p = atomicAdd(&cnt[rows[k] >> 7], 1);
                stage[p] = pack_rec(vals[k], rows[k], cols[k]);
            }
        }
    }
    __syncthreads();

    // identity-coalesced writeout
    for (int i = t; i < len; i += 256)
        staged[(size_t)blk * chunk + i] = stage[i];
}

// ---------------- P4': one-pass distribute (replaces P2+P3+P4) --------------------
// Per bin: scan the 512 run lengths, binary-search gather records from P1's
// staged runs (4-deep for MLP), then write each record DIRECTLY to its final
// global slot via 1024 LDS cursors preloaded from keybase. No LDS data staging,
// no per-bin hist/scan, no overflow path. Writes land in the bin's ~32KB window.
__global__ __launch_bounds__(256) void p4_distribute_kernel(
    const ull* __restrict__ staged, const u16* __restrict__ counts,
    const u16* __restrict__ startpos, const int* __restrict__ keybase,
    ull* __restrict__ recs, int chunk)
{
    __shared__ int doff[NBLK1 + 1];
    __shared__ int srcs[NBLK1];
    __shared__ int cnt[1024];
    __shared__ int s[256];
    const int b = blockIdx.x, t = threadIdx.x;

    // run lengths + starts (coalesced); exclusive scan over 512 runs
    const int la = (int)counts[(size_t)b * NBLK1 + 2 * t];
    const int lb = (int)counts[(size_t)b * NBLK1 + 2 * t + 1];
    srcs[2 * t]     = (int)startpos[(size_t)b * NBLK1 + 2 * t];
    srcs[2 * t + 1] = (int)startpos[(size_t)b * NBLK1 + 2 * t + 1];
    const int mysum = la + lb;
    s[t] = mysum;
    for (int off = 1; off < 256; off <<= 1) {
        __syncthreads();
        const int w = (t >= off) ? s[t - off] : 0;
        __syncthreads();
        s[t] += w;
    }
    const int excl = s[t] - mysum;
    doff[2 * t] = excl;
    doff[2 * t + 1] = excl + la;
    if (t == 255) doff[NBLK1] = s[255];

    // preload global cursors for this bin's 1024 keys (coalesced)
    #pragma unroll
    for (int k = 0; k < 4; ++k)
        cnt[t + k * 256] = keybase[((size_t)b << 10) + t + k * 256];
    __syncthreads();
    const int len = doff[NBLK1];

    // 4-deep gather + direct global scatter
    for (int i0 = 0; i0 < len; i0 += 1024) {
        int idx[4], lo[4], hi[4];
        #pragma unroll
        for (int k = 0; k < 4; ++k) {
            idx[k] = i0 + t + k * 256;
            lo[k] = 0; hi[k] = NBLK1 - 1;
        }
        for (int step = 0; step < 9; ++step) {
            #pragma unroll
            for (int k = 0; k < 4; ++k) {
                if (lo[k] < hi[k]) {
                    const int mid = (lo[k] + hi[k] + 1) >> 1;
                    if (doff[mid] <= idx[k]) lo[k] = mid; else hi[k] = mid - 1;
                }
            }
        }
        ull rr[4];
        #pragma unroll
        for (int k = 0; k < 4; ++k) {
            if (idx[k] < len) {
                const int r = lo[k];
                rr[k] = staged[(size_t)r * chunk + srcs[r] + (idx[k] - doff[r])];
            }
        }
        #pragma unroll
        for (int k = 0; k < 4; ++k) {
            if (idx[k] < len) {
                const int key = ((int)((rr[k] >> 17) & (RB - 1)) << 3) |
                                (int)(((unsigned)rr[k] & 0x1FFFF) >> 14);
                const int p = atomicAdd(&cnt[key], 1);
                recs[p] = rr[k];
            }
        }
    }
}

// ---------------- P0: x -> fp16 (xh reuses the staged region after P4') -----------
__global__ void tohalf_kernel(const float* __restrict__ x,
                              __half2* __restrict__ xh2, int n4)
{
    for (int i = blockIdx.x * blockDim.x + threadIdx.x; i < n4;
         i += gridDim.x * blockDim.x) {
        const float4 v = ((const float4*)x)[i];
        xh2[2 * i + 0] = __floats2half2_rn(v.x, v.y);
        xh2[2 * i + 1] = __floats2half2_rn(v.z, v.w);
    }
}

// ---------------- K6h4: CSR SpMM, quarter-wave half4 gathers, 32 edges in flight ---
// 16 lanes/edge, 8 B/lane (one dwordx2): one gather instruction covers 4 records,
// ILP-8 batch keeps 32 records in flight (2x round-3 MLP, half the VALU/edge).
// XCD-contiguous bijective block swizzle: neighboring rows share their colslice
// working set (~1.6 MB, fits 4 MB per-XCD L2) -> higher L2 hit, lower latency.
__global__ __launch_bounds__(256, 8) void spmm_csr_half4_kernel(
    const h4*  __restrict__ xh4,
    const int* __restrict__ keybase,
    const ull* __restrict__ recs,
    float*     __restrict__ out,
    int n_nodes)
{
    // bijective XCD swizzle (m204): contiguous grid chunk per XCD
    const int nwg = gridDim.x;
    const int q = nwg >> 3, r = nwg & 7;
    const int xcd = blockIdx.x & 7, within = blockIdx.x >> 3;
    const int swz = (xcd < r ? xcd * (q + 1) : r * (q + 1) + (xcd - r) * q) + within;

    const int row = swz * 4 + (threadIdx.x >> 6);
    if (row >= n_nodes) return;
    const int lane = threadIdx.x & 63;
    const int qa = lane >> 4;       // quarter 0..3 -> record j+4k+qa
    const int fl = lane & 15;       // feature block fl*4..fl*4+3

    const int s = keybase[row << 3];
    const int e = keybase[(row << 3) + 8];
    float a0 = 0.f, a1 = 0.f, a2 = 0.f, a3 = 0.f;

    int j = s;
    // full batches: 32 records, 8 gathers in flight
    for (; j + 32 <= e; j += 32) {
        float vv[8]; int aa[8];
        #pragma unroll
        for (int k = 0; k < 8; ++k) {
            const ull rec = recs[j + 4 * k + qa];
            vv[k] = __uint_as_float((unsigned)(rec >> 32));
            aa[k] = ((int)((unsigned)rec & 0x1FFFF) << 4) + fl;
        }
        h4 hv[8];
        #pragma unroll
        for (int k = 0; k < 8; ++k) hv[k] = xh4[aa[k]];   // 8 gathers = 32 recs ISSUED
        __builtin_amdgcn_sched_barrier(0);                // ...kept in flight
        #pragma unroll
        for (int k = 0; k < 8; ++k) {
            const float2 flo = __half22float2(hv[k].lo);
            const float2 fhi = __half22float2(hv[k].hi);
            a0 = fmaf(vv[k], flo.x, a0);
            a1 = fmaf(vv[k], flo.y, a1);
            a2 = fmaf(vv[k], fhi.x, a2);
            a3 = fmaf(vv[k], fhi.y, a3);
        }
    }
    // single masked batch for the tail: pipeline stays 8-deep
    if (j < e) {
        const int safe = e - 1;
        float vv[8]; int aa[8];
        #pragma unroll
        for (int k = 0; k < 8; ++k) {
            const int  idx = j + 4 * k + qa;
            const bool ok  = idx < e;
            const ull  rec = recs[ok ? idx : safe];
            vv[k] = ok ? __uint_as_float((unsigned)(rec >> 32)) : 0.f;
            aa[k] = ((int)((unsigned)rec & 0x1FFFF) << 4) + fl;
        }
        h4 hv[8];
        #pragma unroll
        for (int k = 0; k < 8; ++k) hv[k] = xh4[aa[k]];
        __builtin_amdgcn_sched_barrier(0);
        #pragma unroll
        for (int k = 0; k < 8; ++k) {
            const float2 flo = __half22float2(hv[k].lo);
            const float2 fhi = __half22float2(hv[k].hi);
            a0 = fmaf(vv[k], flo.x, a0);
            a1 = fmaf(vv[k], flo.y, a1);
            a2 = fmaf(vv[k], fhi.x, a2);
            a3 = fmaf(vv[k], fhi.y, a3);
        }
    }

    // reduce across the 4 quarters (lanes fl, fl+16, fl+32, fl+48)
    a0 += __shfl_xor(a0, 16); a0 += __shfl_xor(a0, 32);
    a1 += __shfl_xor(a1, 16); a1 += __shfl_xor(a1, 32);
    a2 += __shfl_xor(a2, 16); a2 += __shfl_xor(a2, 32);
    a3 += __shfl_xor(a3, 16); a3 += __shfl_xor(a3, 32);
    if (qa == 0) {
        float4 o; o.x = a0; o.y = a1; o.z = a2; o.w = a3;
        ((float4*)out)[(size_t)row * 16 + fl] = o;
    }
}

static inline size_t align16(size_t v) { return (v + 15) & ~(size_t)15; }

extern "C" void kernel_launch(void* const* d_in, const int* in_sizes, int n_in,
                              void* d_out, int out_size, void* d_ws, size_t ws_size,
                              hipStream_t stream)
{
    // setup_inputs order: t, x, edge_row, edge_col, edge_val
    const float* x        = (const float*)d_in[1];
    const int*   edge_row = (const int*)d_in[2];
    const int*   edge_col = (const int*)d_in[3];
    const float* edge_val = (const float*)d_in[4];
    float*       out      = (float*)d_out;

    const int n_edges = in_sizes[2];
    const int n_nodes = out_size / D;
    const int nb      = (n_nodes + RB - 1) / RB;
    const int nkeys   = nb << 10;                 // bin-padded (row<<3)|slice keys
    const int nscan1  = (nkeys + 4095) >> 12;
    const int chunk   = (((n_edges + NBLK1 - 1) / NBLK1) + 3) & ~3;  // x4 for int4

    // workspace carve
    const size_t off_recs   = 0;                                              // n_edges*8
    const size_t off_staged = align16(off_recs + (size_t)n_edges * 8);        // NBLK1*chunk*8 (xh reuse)
    const size_t off_counts = align16(off_staged + (size_t)NBLK1 * chunk * 8);// nb*NBLK1 u16
    const size_t off_start  = align16(off_counts + (size_t)nb * NBLK1 * 2);   // nb*NBLK1 u16
    const size_t off_keyb   = align16(off_start + (size_t)nb * NBLK1 * 2);    // (nkeys+1)*4
    const size_t off_hist   = align16(off_keyb + (size_t)(nkeys + 1) * 4);    // nkeys*4
    const size_t off_sums   = align16(off_hist + (size_t)nkeys * 4);          // nscan1*4
    const size_t ws_needed  = off_sums + (size_t)nscan1 * 4;
    const size_t xh_bytes   = (size_t)n_nodes * D * 2;   // must fit in staged region

    if (ws_size < ws_needed || nb > NB_MAX || n_nodes > (1 << 17) ||
        chunk > P1CAP || n_edges < 1 || nscan1 > 256 ||
        xh_bytes > (size_t)NBLK1 * chunk * 8) {
        hipMemsetAsync(out, 0, (size_t)out_size * sizeof(float), stream);
        const int n_blocks = (n_edges + 3) / 4;
        spmm_atomic_kernel<<<n_blocks, 256, 0, stream>>>(
            x, edge_row, edge_col, edge_val, out, n_edges);
        return;
    }

    char* ws = (char*)d_ws;
    ull*    recs     = (ull*)(ws + off_recs);
    ull*    staged   = (ull*)(ws + off_staged);
    u16*    counts   = (u16*)(ws + off_counts);
    u16*    startpos = (u16*)(ws + off_start);
    int*    keybase  = (int*)(ws + off_keyb);
    int*    hist     = (int*)(ws + off_hist);
    int*    sums     = (int*)(ws + off_sums);
    __half* xh       = (__half*)(ws + off_staged);   // reuses staged AFTER P4'

    const int n_eblk = (n_edges + 1023) / 1024;      // 4 edges/thread

    // RH: global key histogram (independent of P1)
    hipMemsetAsync(hist, 0, (size_t)nkeys * 4, stream);
    hist_kernel<<<n_eblk, 256, 0, stream>>>(edge_row, edge_col, hist, n_edges);
    // S1..S3: exclusive scan -> keybase (+ sentinel)
    scan1_kernel<<<nscan1, 1024, 0, stream>>>(hist, keybase, sums, nkeys);
    scan2_kernel<<<1, 256, 0, stream>>>(sums, nscan1);
    scan3_kernel<<<(nkeys + 1023) / 1024, 256, 0, stream>>>(
        keybase, sums, nkeys, n_edges);
    // P1: per-block LDS counting sort -> staged (all record writes coalesced)
    p1_localsort_kernel<<<NBLK1, 256, 0, stream>>>(
        edge_row, edge_col, edge_val, staged, counts, startpos,
        n_edges, nb, chunk);
    // P4': one-pass gather + direct global scatter to final (row,colslice) order
    p4_distribute_kernel<<<nb, 256, 0, stream>>>(
        staged, counts, startpos, keybase, recs, chunk);
    // P0: x -> fp16 into the (now free) staged region
    const int n4 = (n_nodes * D) / 4;
    tohalf_kernel<<<2048, 256, 0, stream>>>(x, (__half2*)xh, n4);
    // K6h4: CSR SpMM, quarter-wave half4 gathers + XCD swizzle
    spmm_csr_half4_kernel<<<(n_nodes + 3) / 4, 256, 0, stream>>>(
        (const h4*)xh, keybase, recs, out, n_nodes);
}

// Round 5
// 271.794 us; speedup vs baseline: 1.3657x; 1.3657x over previous
//
#include <hip/hip_runtime.h>
#include <hip/hip_bf16.h>
#include <hip/hip_fp16.h>

#define D 64
#define RB 128            // rows per bin (7-bit local row)
#define NB_MAX 1024       // max bins (n_nodes <= 2^17)
#define NBLK1 512         // P1 blocks (2/CU, 8 waves/CU)
#define P1CAP 6272        // P1 LDS stage capacity (recs) = 50,176 B
#define CAP 5120          // P4 LDS stage capacity (recs) = 40 KB

typedef unsigned long long ull;
typedef unsigned short u16;

// rec = [ val:f32 (hi32) | localrow:bits17-23 | col:bits0-16 ]
__device__ __forceinline__ ull pack_rec(float v, int r, int c) {
    return ((ull)__float_as_uint(v) << 32) |
           (ull)(((unsigned)(r & (RB - 1)) << 17) | (unsigned)c);
}

// ---------------- fallback: atomic kernel (guard path) ----------------
__global__ __launch_bounds__(256) void spmm_atomic_kernel(
    const float* __restrict__ x,
    const int*   __restrict__ edge_row,
    const int*   __restrict__ edge_col,
    const float* __restrict__ edge_val,
    float*       __restrict__ out,
    int n_edges)
{
    const int gtid = blockIdx.x * blockDim.x + threadIdx.x;
    const int wave = gtid >> 6;
    const int lane = threadIdx.x & 63;
    if (wave >= n_edges) return;
    const int   r = edge_row[wave];
    const int   c = edge_col[wave];
    const float v = edge_val[wave];
    atomicAdd(&out[(size_t)r * D + lane], v * x[(size_t)c * D + lane]);
}

// ---------------- P1: per-block LDS counting sort + identity-coalesced writeout ----
// counts/startpos layout: [bin][blk] (transposed) -> P2/P4 reads coalesced;
// P1's strided u16 writes hit a 100KB L2-resident array (absorbed).
__global__ __launch_bounds__(256) void p1_localsort_kernel(
    const int* __restrict__ rows, const int* __restrict__ cols,
    const float* __restrict__ vals,
    ull* __restrict__ staged, u16* __restrict__ counts, u16* __restrict__ startpos,
    int n_edges, int nb, int chunk)
{
    __shared__ ull stage[P1CAP];
    __shared__ int cnt[NB_MAX];
    __shared__ int s[256];
    const int t = threadIdx.x, blk = blockIdx.x;
    const int e0 = blk * chunk;
    const int e1 = min(e0 + chunk, n_edges);
    const int len = e1 - e0;

    for (int i = t; i < nb; i += 256) cnt[i] = 0;
    __syncthreads();

    // pass 1: histogram rows (int4)
    for (int i = e0 + t * 4; i < e1; i += 1024) {
        if (i + 4 <= e1) {
            const int4 r4 = *(const int4*)(rows + i);
            atomicAdd(&cnt[r4.x >> 7], 1);
            atomicAdd(&cnt[r4.y >> 7], 1);
            atomicAdd(&cnt[r4.z >> 7], 1);
            atomicAdd(&cnt[r4.w >> 7], 1);
        } else {
            for (int k = i; k < e1; ++k) atomicAdd(&cnt[rows[k] >> 7], 1);
        }
    }
    __syncthreads();

    // write counts + in-place exclusive scan of cnt
    int pre[4], sum = 0;
    const int base = t * 4;
    #pragma unroll
    for (int k = 0; k < 4; ++k) {
        const int idx = base + k;
        const int c = (idx < nb) ? cnt[idx] : 0;
        if (idx < nb) counts[(size_t)idx * NBLK1 + blk] = (u16)c;
        pre[k] = sum; sum += c;
    }
    s[t] = sum;
    for (int off = 1; off < 256; off <<= 1) {
        __syncthreads();
        const int w = (t >= off) ? s[t - off] : 0;
        __syncthreads();
        s[t] += w;
    }
    const int texcl = s[t] - sum;
    __syncthreads();
    #pragma unroll
    for (int k = 0; k < 4; ++k) {
        const int idx = base + k;
        if (idx < nb) {
            const int e = texcl + pre[k];
            cnt[idx] = e;                                   // becomes cursor
            startpos[(size_t)idx * NBLK1 + blk] = (u16)e;
        }
    }
    __syncthreads();

    // pass 2: scatter into LDS stage
    for (int i = e0 + t * 4; i < e1; i += 1024) {
        if (i + 4 <= e1) {
            const int4   r4 = *(const int4*)(rows + i);
            const int4   c4 = *(const int4*)(cols + i);
            const float4 v4 = *(const float4*)(vals + i);
            int p;
            p = atomicAdd(&cnt[r4.x >> 7], 1); stage[p] = pack_rec(v4.x, r4.x, c4.x);
            p = atomicAdd(&cnt[r4.y >> 7], 1); stage[p] = pack_rec(v4.y, r4.y, c4.y);
            p = atomicAdd(&cnt[r4.z >> 7], 1); stage[p] = pack_rec(v4.z, r4.z, c4.z);
            p = atomicAdd(&cnt[r4.w >> 7], 1); stage[p] = pack_rec(v4.w, r4.w, c4.w);
        } else {
            for (int k = i; k < e1; ++k) {
                const int p = atomicAdd(&cnt[rows[k] >> 7], 1);
                stage[p] = pack_rec(vals[k], rows[k], cols[k]);
            }
        }
    }
    __syncthreads();

    // identity-coalesced writeout
    for (int i = t; i < len; i += 256)
        staged[(size_t)blk * chunk + i] = stage[i];
}

// ---------------- P2: binsum[b] = sum over blocks of counts[b][blk] (coalesced) ----
__global__ __launch_bounds__(256) void p2_binsum_kernel(
    const u16* __restrict__ counts, int* __restrict__ binsum, int nb)
{
    __shared__ int s[256];
    const int b = blockIdx.x, t = threadIdx.x;
    const int acc = (int)counts[(size_t)b * NBLK1 + t] +
                    (int)counts[(size_t)b * NBLK1 + t + 256];
    s[t] = acc;
    __syncthreads();
    for (int off = 128; off > 0; off >>= 1) {
        if (t < off) s[t] += s[t + off];
        __syncthreads();
    }
    if (t == 0) binsum[b] = s[0];
}

// ---------------- P3: exclusive scan over bins -> binbase[nb+1]; zero flags --------
__global__ __launch_bounds__(1024) void p3_scanbins_kernel(
    const int* __restrict__ binsum, int* __restrict__ binbase,
    int* __restrict__ flags, int nb)
{
    __shared__ int s[1024];
    const int t = threadIdx.x;
    const int mine = (t < nb) ? binsum[t] : 0;
    s[t] = mine;
    for (int off = 1; off < 1024; off <<= 1) {
        __syncthreads();
        const int v = (t >= off) ? s[t - off] : 0;
        __syncthreads();
        s[t] += v;
    }
    if (t < nb) { binbase[t] = s[t] - mine; flags[t] = 0; }
    if (t == nb - 1) binbase[nb] = s[t];
}

// ---------------- P4: per-bin gather + LDS key-sort (localrow | colslice) ----------
__global__ __launch_bounds__(256) void p4_binsort_kernel(
    const ull* __restrict__ staged, const u16* __restrict__ counts,
    const u16* __restrict__ startpos, const int* __restrict__ binbase,
    ull* __restrict__ recs, int* __restrict__ offsets_row, int* __restrict__ flags,
    int nb, int n_nodes, int chunk)
{
    __shared__ ull stage[CAP];
    __shared__ int doff[NBLK1 + 1];
    __shared__ int srcs[NBLK1];
    __shared__ int cnt[1024];
    __shared__ int s[256];
    const int b = blockIdx.x, t = threadIdx.x;
    const int s0 = binbase[b];

    // load run lengths + starts (coalesced); exclusive scan over 512 runs
    const int la = (int)counts[(size_t)b * NBLK1 + 2 * t];
    const int lb = (int)counts[(size_t)b * NBLK1 + 2 * t + 1];
    srcs[2 * t]     = (int)startpos[(size_t)b * NBLK1 + 2 * t];
    srcs[2 * t + 1] = (int)startpos[(size_t)b * NBLK1 + 2 * t + 1];
    const int mysum = la + lb;
    s[t] = mysum;
    for (int off = 1; off < 256; off <<= 1) {
        __syncthreads();
        const int w = (t >= off) ? s[t - off] : 0;
        __syncthreads();
        s[t] += w;
    }
    const int excl = s[t] - mysum;
    doff[2 * t] = excl;
    doff[2 * t + 1] = excl + la;
    if (t == 255) doff[NBLK1] = s[255];
    __syncthreads();
    const int len = doff[NBLK1];

    if (len > CAP) {
        // overflow: bin-grouped raw copy (K6 filter path)
        if (t == 0) flags[b] = 1;
        for (int i = t; i < len; i += 256) {
            int lo = 0, hi = NBLK1 - 1;
            while (lo < hi) {
                const int mid = (lo + hi + 1) >> 1;
                if (doff[mid] <= i) lo = mid; else hi = mid - 1;
            }
            recs[s0 + i] = staged[(size_t)lo * chunk + srcs[lo] + (i - doff[lo])];
        }
        if (t == 0 && b * RB <= n_nodes) offsets_row[b * RB] = s0;
        return;
    }

    for (int i = t; i < 1024; i += 256) cnt[i] = 0;
    __syncthreads();

    // gather runs into LDS + key histogram
    for (int i = t; i < len; i += 256) {
        int lo = 0, hi = NBLK1 - 1;
        while (lo < hi) {
            const int mid = (lo + hi + 1) >> 1;
            if (doff[mid] <= i) lo = mid; else hi = mid - 1;
        }
        const ull rr = staged[(size_t)lo * chunk + srcs[lo] + (i - doff[lo])];
        stage[i] = rr;
        const int key = ((int)((rr >> 17) & (RB - 1)) << 3) |
                        (int)(((unsigned)rr & 0x1FFFF) >> 14);
        atomicAdd(&cnt[key], 1);
    }
    __syncthreads();

    // exclusive scan of 1024 keys (4 per thread) -> cnt becomes cursor
    int v[4], pre[4], sum = 0;
    const int base = t * 4;
    #pragma unroll
    for (int k = 0; k < 4; ++k) { v[k] = cnt[base + k]; pre[k] = sum; sum += v[k]; }
    s[t] = sum;
    for (int off = 1; off < 256; off <<= 1) {
        __syncthreads();
        const int w = (t >= off) ? s[t - off] : 0;
        __syncthreads();
        s[t] += w;
    }
    const int texcl = s[t] - sum;
    __syncthreads();
    #pragma unroll
    for (int k = 0; k < 4; ++k) cnt[base + k] = texcl + pre[k];
    __syncthreads();

    // emit row offsets (row lr starts at key lr*8)
    if (t <= RB) {
        const int r = b * RB + t;
        if (r <= n_nodes)
            offsets_row[r] = s0 + ((t == RB) ? len : cnt[t << 3]);
    }
    __syncthreads();

    // permute to final (localrow, colslice) order
    for (int i = t; i < len; i += 256) {
        const ull rr = stage[i];
        const int key = ((int)((rr >> 17) & (RB - 1)) << 3) |
                        (int)(((unsigned)rr & 0x1FFFF) >> 14);
        const int p = atomicAdd(&cnt[key], 1);
        recs[s0 + p] = rr;
    }
}

// ---------------- P0: x -> fp16 (xh reuses the staged region after P4) -------------
__global__ void tohalf_kernel(const float* __restrict__ x,
                              __half2* __restrict__ xh2, int n4)
{
    for (int i = blockIdx.x * blockDim.x + threadIdx.x; i < n4;
         i += gridDim.x * blockDim.x) {
        const float4 v = ((const float4*)x)[i];
        xh2[2 * i + 0] = __floats2half2_rn(v.x, v.y);
        xh2[2 * i + 1] = __floats2half2_rn(v.z, v.w);
    }
}

// ---------------- K6p: CSR SpMM, per-row fully-issued gather pipeline --------------
// Round-3 evidence: K6h2 at 84us with VALUBusy 39%, hbm 28%, occ 73% -> nothing
// saturated; each row's 2-3 batches were SERIAL latency chains (~600cy each).
// Fix: rows average 32 edges (Poisson, std 5.7); 3 masked 16-edge batches cover
// 99.6% of rows. Issue ALL 24 gathers up front, sched_barrier, then consume in
// order -> compiler emits counted vmcnt(16)/vmcnt(8)/vmcnt(0): ONE latency chain
// per row. Rare >48-edge rows fall to a serial loop.
#define K6_LI(vv, hv, jj)                                              \
    {                                                                  \
        int aa[8];                                                     \
        _Pragma("unroll")                                              \
        for (int k = 0; k < 8; ++k) {                                  \
            const int  idx = (jj) + 2 * k + half;                      \
            const bool ok  = idx < e;                                  \
            const ull  rec = recs[ok ? idx : safe];                    \
            vv[k] = ok ? __uint_as_float((unsigned)(rec >> 32)) : 0.f; \
            aa[k] = ((int)((unsigned)rec & 0x1FFFF) << 5) + fl;        \
        }                                                              \
        _Pragma("unroll")                                              \
        for (int k = 0; k < 8; ++k) hv[k] = xh2[aa[k]];                \
    }

#define K6_CONSUME(vv, hv)                                             \
    {                                                                  \
        _Pragma("unroll")                                              \
        for (int k = 0; k < 8; ++k) {                                  \
            const float2 xf = __half22float2(hv[k]);                   \
            accx = fmaf(vv[k], xf.x, accx);                            \
            accy = fmaf(vv[k], xf.y, accy);                            \
        }                                                              \
    }

__global__ __launch_bounds__(256, 4) void spmm_csr_half2_kernel(
    const __half* __restrict__ xh,
    const int*   __restrict__ offsets_row,
    const int*   __restrict__ binbase,
    const ull*   __restrict__ recs,
    const int*   __restrict__ flags,
    float*       __restrict__ out,
    int n_nodes)
{
    const int row  = blockIdx.x * 4 + (threadIdx.x >> 6);
    if (row >= n_nodes) return;
    const int lane = threadIdx.x & 63;
    const int b    = row >> 7;

    if (__builtin_expect(flags[b], 0)) {
        // overflow path: unsorted bin-grouped records, full-wave scalar
        float acc = 0.f;
        const int s  = binbase[b];
        const int e  = binbase[b + 1];
        const int lr = row & (RB - 1);
        for (int j = s; j < e; ++j) {
            const ull rec = recs[j];
            if ((int)((rec >> 17) & (RB - 1)) == lr) {
                const int   c = (int)((unsigned)rec & 0x1FFFF);
                const float v = __uint_as_float((unsigned)(rec >> 32));
                acc += v * __half2float(xh[(size_t)c * D + lane]);
            }
        }
        out[(size_t)row * D + lane] = acc;
        return;
    }

    const __half2* xh2 = (const __half2*)xh;
    const int half = lane >> 5;
    const int fl   = lane & 31;

    const int s = offsets_row[row];
    const int e = offsets_row[row + 1];
    float accx = 0.f, accy = 0.f;

    if (e > s) {
        const int safe = e - 1;
        float   vvA[8], vvB[8], vvC[8];
        __half2 hvA[8], hvB[8], hvC[8];
        // issue everything for this row (masked batches; 48 edges covers 99.6%)
        K6_LI(vvA, hvA, s);
        K6_LI(vvB, hvB, s + 16);
        K6_LI(vvC, hvC, s + 32);
        __builtin_amdgcn_sched_barrier(0);
        // consume in order: vmcnt(16) -> vmcnt(8) -> vmcnt(0)
        K6_CONSUME(vvA, hvA);
        K6_CONSUME(vvB, hvB);
        K6_CONSUME(vvC, hvC);
        if (__builtin_expect(e - s > 48, 0)) {
            // rare long row: serial batches for the remainder
            int j = s + 48;
            for (; j + 16 <= e; j += 16) {
                K6_LI(vvA, hvA, j);
                __builtin_amdgcn_sched_barrier(0);
                K6_CONSUME(vvA, hvA);
            }
            if (j < e) {
                K6_LI(vvA, hvA, j);
                K6_CONSUME(vvA, hvA);
            }
        }
    }

    accx += __shfl_xor(accx, 32);
    accy += __shfl_xor(accy, 32);
    if (half == 0) {
        float2 o; o.x = accx; o.y = accy;
        ((float2*)out)[(size_t)row * 32 + fl] = o;
    }
}

static inline size_t align16(size_t v) { return (v + 15) & ~(size_t)15; }

extern "C" void kernel_launch(void* const* d_in, const int* in_sizes, int n_in,
                              void* d_out, int out_size, void* d_ws, size_t ws_size,
                              hipStream_t stream)
{
    // setup_inputs order: t, x, edge_row, edge_col, edge_val
    const float* x        = (const float*)d_in[1];
    const int*   edge_row = (const int*)d_in[2];
    const int*   edge_col = (const int*)d_in[3];
    const float* edge_val = (const float*)d_in[4];
    float*       out      = (float*)d_out;

    const int n_edges = in_sizes[2];
    const int n_nodes = out_size / D;
    const int nb      = (n_nodes + RB - 1) / RB;
    const int chunk   = (((n_edges + NBLK1 - 1) / NBLK1) + 3) & ~3;  // x4 for int4

    // workspace carve
    const size_t off_recs    = 0;                                               // n_edges*8
    const size_t off_staged  = align16(off_recs + (size_t)n_edges * 8);         // NBLK1*chunk*8 (xh reuse)
    const size_t off_counts  = align16(off_staged + (size_t)NBLK1 * chunk * 8); // nb*NBLK1 u16
    const size_t off_start   = align16(off_counts + (size_t)nb * NBLK1 * 2);    // nb*NBLK1 u16
    const size_t off_binsum  = align16(off_start + (size_t)nb * NBLK1 * 2);     // nb ints
    const size_t off_binbase = align16(off_binsum + (size_t)nb * 4);            // nb+1 ints
    const size_t off_rowoffs = align16(off_binbase + (size_t)(nb + 1) * 4);     // n_nodes+1 ints
    const size_t off_flags   = align16(off_rowoffs + (size_t)(n_nodes + 1) * 4);// nb ints
    const size_t ws_needed   = off_flags + (size_t)nb * 4;
    const size_t xh_bytes    = (size_t)n_nodes * D * 2;   // must fit in staged region

    if (ws_size < ws_needed || nb > NB_MAX || n_nodes > (1 << 17) ||
        chunk > P1CAP || xh_bytes > (size_t)NBLK1 * chunk * 8) {
        hipMemsetAsync(out, 0, (size_t)out_size * sizeof(float), stream);
        const int n_blocks = (n_edges + 3) / 4;
        spmm_atomic_kernel<<<n_blocks, 256, 0, stream>>>(
            x, edge_row, edge_col, edge_val, out, n_edges);
        return;
    }

    char* ws = (char*)d_ws;
    ull*    recs        = (ull*)(ws + off_recs);
    ull*    staged      = (ull*)(ws + off_staged);
    u16*    counts      = (u16*)(ws + off_counts);
    u16*    startpos    = (u16*)(ws + off_start);
    int*    binsum      = (int*)(ws + off_binsum);
    int*    binbase     = (int*)(ws + off_binbase);
    int*    offsets_row = (int*)(ws + off_rowoffs);
    int*    flags       = (int*)(ws + off_flags);
    __half* xh          = (__half*)(ws + off_staged);   // reuses staged AFTER P4

    // P1: per-block LDS counting sort -> staged (all record writes coalesced)
    p1_localsort_kernel<<<NBLK1, 256, 0, stream>>>(
        edge_row, edge_col, edge_val, staged, counts, startpos,
        n_edges, nb, chunk);
    // P2: per-bin totals
    p2_binsum_kernel<<<nb, 256, 0, stream>>>(counts, binsum, nb);
    // P3: bin bases + flag zeroing
    p3_scanbins_kernel<<<1, 1024, 0, stream>>>(binsum, binbase, flags, nb);
    // P4: gather runs + sort by (localrow | colslice) -> final recs + row offsets
    p4_binsort_kernel<<<nb, 256, 0, stream>>>(
        staged, counts, startpos, binbase, recs, offsets_row, flags,
        nb, n_nodes, chunk);
    // P0: x -> fp16 into the (now free) staged region
    const int n4 = (n_nodes * D) / 4;
    tohalf_kernel<<<2048, 256, 0, stream>>>(x, (__half2*)xh, n4);
    // K6p: CSR SpMM, per-row fully-issued gather pipeline
    spmm_csr_half2_kernel<<<(n_nodes + 3) / 4, 256, 0, stream>>>(
        xh, offsets_row, binbase, recs, flags, out, n_nodes);
}

// Round 6
// 245.892 us; speedup vs baseline: 1.5096x; 1.1053x over previous
//
#include <hip/hip_runtime.h>
#include <hip/hip_bf16.h>
#include <hip/hip_fp16.h>

#define D 64
#define RB 128            // rows per bin (7-bit local row)
#define NB_MAX 1024       // max bins (n_nodes <= 2^17)
#define NBLK1 512         // P1a/P1b blocks (2/CU)
#define P1CAP 6272        // P1b LDS stage capacity (recs) = 50,176 B
#define CAP 5120          // P4' LDS stage capacity (recs) = 40 KB

typedef unsigned long long ull;
typedef unsigned short u16;

// rec = [ val:f32 (hi32) | localrow:bits17-23 | col:bits0-16 ]
__device__ __forceinline__ ull pack_rec(float v, int r, int c) {
    return ((ull)__float_as_uint(v) << 32) |
           (ull)(((unsigned)(r & (RB - 1)) << 17) | (unsigned)c);
}

// ---------------- fallback: atomic kernel (guard path) ----------------
__global__ __launch_bounds__(256) void spmm_atomic_kernel(
    const float* __restrict__ x,
    const int*   __restrict__ edge_row,
    const int*   __restrict__ edge_col,
    const float* __restrict__ edge_val,
    float*       __restrict__ out,
    int n_edges)
{
    const int gtid = blockIdx.x * blockDim.x + threadIdx.x;
    const int wave = gtid >> 6;
    const int lane = threadIdx.x & 63;
    if (wave >= n_edges) return;
    const int   r = edge_row[wave];
    const int   c = edge_col[wave];
    const float v = edge_val[wave];
    atomicAdd(&out[(size_t)r * D + lane], v * x[(size_t)c * D + lane]);
}

// ---------------- P1a: per-block row histogram -> counts[bin][blk] ----------------
__global__ __launch_bounds__(256) void p1a_hist_kernel(
    const int* __restrict__ rows, u16* __restrict__ counts,
    int n_edges, int nb, int chunk)
{
    __shared__ int cnt[NB_MAX];
    const int t = threadIdx.x, blk = blockIdx.x;
    const int e0 = blk * chunk;
    const int e1 = min(e0 + chunk, n_edges);

    for (int i = t; i < nb; i += 256) cnt[i] = 0;
    __syncthreads();

    for (int i = e0 + t * 4; i < e1; i += 1024) {
        if (i + 4 <= e1) {
            const int4 r4 = *(const int4*)(rows + i);
            atomicAdd(&cnt[r4.x >> 7], 1);
            atomicAdd(&cnt[r4.y >> 7], 1);
            atomicAdd(&cnt[r4.z >> 7], 1);
            atomicAdd(&cnt[r4.w >> 7], 1);
        } else {
            for (int k = i; k < e1; ++k) atomicAdd(&cnt[rows[k] >> 7], 1);
        }
    }
    __syncthreads();

    for (int i = t; i < nb; i += 256)
        counts[(size_t)i * NBLK1 + blk] = (u16)cnt[i];
}

// ---------------- P2': per-bin exclusive scan over 512 blocks -> dest32, binsum ----
// dest32[bin][blk] = #records of bin in blocks < blk. Coalesced read AND write.
__global__ __launch_bounds__(256) void p2_scanblocks_kernel(
    const u16* __restrict__ counts, int* __restrict__ dest32,
    int* __restrict__ binsum, int nb)
{
    __shared__ int s[256];
    const int b = blockIdx.x, t = threadIdx.x;
    const int la = (int)counts[(size_t)b * NBLK1 + 2 * t];
    const int lb = (int)counts[(size_t)b * NBLK1 + 2 * t + 1];
    const int mysum = la + lb;
    s[t] = mysum;
    for (int off = 1; off < 256; off <<= 1) {
        __syncthreads();
        const int w = (t >= off) ? s[t - off] : 0;
        __syncthreads();
        s[t] += w;
    }
    const int excl = s[t] - mysum;
    dest32[(size_t)b * NBLK1 + 2 * t]     = excl;
    dest32[(size_t)b * NBLK1 + 2 * t + 1] = excl + la;
    if (t == 255) binsum[b] = s[255];
}

// ---------------- P3: exclusive scan over bins -> binbase[nb+1]; zero flags --------
__global__ __launch_bounds__(1024) void p3_scanbins_kernel(
    const int* __restrict__ binsum, int* __restrict__ binbase,
    int* __restrict__ flags, int nb)
{
    __shared__ int s[1024];
    const int t = threadIdx.x;
    const int mine = (t < nb) ? binsum[t] : 0;
    s[t] = mine;
    for (int off = 1; off < 1024; off <<= 1) {
        __syncthreads();
        const int v = (t >= off) ? s[t - off] : 0;
        __syncthreads();
        s[t] += v;
    }
    if (t < nb) { binbase[t] = s[t] - mine; flags[t] = 0; }
    if (t == nb - 1) binbase[nb] = s[t];
}

// ---------------- P1b: LDS counting sort + DIRECT write to final bin slots ---------
// Replaces old P1's staged round-trip + P4's binary-search run-gather: every run's
// global destination is binbase[bin] + dest32[bin][blk], known up front. Run writes
// are consecutive recs (coalesced within ~100B runs) into the bin's final region.
__global__ __launch_bounds__(256) void p1b_sortwrite_kernel(
    const int* __restrict__ rows, const int* __restrict__ cols,
    const float* __restrict__ vals,
    const u16* __restrict__ counts, const int* __restrict__ dest32,
    const int* __restrict__ binbase,
    ull* __restrict__ recs, int n_edges, int nb, int chunk)
{
    __shared__ ull stage[P1CAP];
    __shared__ u16 binof[P1CAP];
    __shared__ int cnt[NB_MAX];     // cursors
    __shared__ u16 doffL[NB_MAX];   // local run starts (snapshot)
    __shared__ int gbase[NB_MAX];   // global run bases
    __shared__ int s[256];
    const int t = threadIdx.x, blk = blockIdx.x;
    const int e0 = blk * chunk;
    const int e1 = min(e0 + chunk, n_edges);
    const int len = e1 - e0;

    // rebuild local cursors from counts (no re-histogram): scan 1024 bins
    int pre[4], sum = 0, c4[4];
    const int base = t * 4;
    #pragma unroll
    for (int k = 0; k < 4; ++k) {
        const int idx = base + k;
        c4[k] = (idx < nb) ? (int)counts[(size_t)idx * NBLK1 + blk] : 0;
        pre[k] = sum; sum += c4[k];
    }
    s[t] = sum;
    for (int off = 1; off < 256; off <<= 1) {
        __syncthreads();
        const int w = (t >= off) ? s[t - off] : 0;
        __syncthreads();
        s[t] += w;
    }
    const int texcl = s[t] - sum;
    __syncthreads();
    #pragma unroll
    for (int k = 0; k < 4; ++k) {
        const int idx = base + k;
        if (idx < nb) {
            const int e = texcl + pre[k];
            cnt[idx]   = e;
            doffL[idx] = (u16)e;
            gbase[idx] = binbase[idx] + dest32[(size_t)idx * NBLK1 + blk];
        }
    }
    __syncthreads();

    // scatter into LDS stage, remembering each slot's bin
    for (int i = e0 + t * 4; i < e1; i += 1024) {
        if (i + 4 <= e1) {
            const int4   r4 = *(const int4*)(rows + i);
            const int4   c4v = *(const int4*)(cols + i);
            const float4 v4 = *(const float4*)(vals + i);
            int p;
            p = atomicAdd(&cnt[r4.x >> 7], 1); stage[p] = pack_rec(v4.x, r4.x, c4v.x); binof[p] = (u16)(r4.x >> 7);
            p = atomicAdd(&cnt[r4.y >> 7], 1); stage[p] = pack_rec(v4.y, r4.y, c4v.y); binof[p] = (u16)(r4.y >> 7);
            p = atomicAdd(&cnt[r4.z >> 7], 1); stage[p] = pack_rec(v4.z, r4.z, c4v.z); binof[p] = (u16)(r4.z >> 7);
            p = atomicAdd(&cnt[r4.w >> 7], 1); stage[p] = pack_rec(v4.w, r4.w, c4v.w); binof[p] = (u16)(r4.w >> 7);
        } else {
            for (int k = i; k < e1; ++k) {
                const int p = atomicAdd(&cnt[rows[k] >> 7], 1);
                stage[p] = pack_rec(vals[k], rows[k], cols[k]);
                binof[p] = (u16)(rows[k] >> 7);
            }
        }
    }
    __syncthreads();

    // writeout: run-contiguous into final bin regions
    for (int i = t; i < len; i += 256) {
        const int bin = (int)binof[i];
        const int g   = gbase[bin] + (i - (int)doffL[bin]);
        recs[g] = stage[i];
    }
}

// ---------------- P4': per-bin IN-PLACE key-sort (localrow | colslice) -------------
// Input is already bin-contiguous: coalesced read, LDS sort, coalesced-window write.
__global__ __launch_bounds__(256) void p4_sortbin_kernel(
    const int* __restrict__ binbase,
    ull* __restrict__ recs, int* __restrict__ offsets_row, int* __restrict__ flags,
    int n_nodes)
{
    __shared__ ull stage[CAP];
    __shared__ int cnt[1024];
    __shared__ int s[256];
    const int b = blockIdx.x, t = threadIdx.x;
    const int s0  = binbase[b];
    const int len = binbase[b + 1] - s0;

    if (len > CAP) {
        // overflow: leave bin unsorted (already grouped); K6 filter path handles it
        if (t == 0) {
            flags[b] = 1;
            if (b * RB <= n_nodes) offsets_row[b * RB] = s0;
        }
        return;
    }

    for (int i = t; i < 1024; i += 256) cnt[i] = 0;
    __syncthreads();

    // contiguous read + key histogram
    for (int i = t; i < len; i += 256) {
        const ull rr = recs[s0 + i];
        stage[i] = rr;
        const int key = ((int)((rr >> 17) & (RB - 1)) << 3) |
                        (int)(((unsigned)rr & 0x1FFFF) >> 14);
        atomicAdd(&cnt[key], 1);
    }
    __syncthreads();

    // exclusive scan of 1024 keys (4 per thread) -> cnt becomes cursor
    int v[4], pre[4], sum = 0;
    const int base = t * 4;
    #pragma unroll
    for (int k = 0; k < 4; ++k) { v[k] = cnt[base + k]; pre[k] = sum; sum += v[k]; }
    s[t] = sum;
    for (int off = 1; off < 256; off <<= 1) {
        __syncthreads();
        const int w = (t >= off) ? s[t - off] : 0;
        __syncthreads();
        s[t] += w;
    }
    const int texcl = s[t] - sum;
    __syncthreads();
    #pragma unroll
    for (int k = 0; k < 4; ++k) cnt[base + k] = texcl + pre[k];
    __syncthreads();

    // emit row offsets (row lr starts at key lr*8)
    if (t <= RB) {
        const int r = b * RB + t;
        if (r <= n_nodes)
            offsets_row[r] = s0 + ((t == RB) ? len : cnt[t << 3]);
    }
    __syncthreads();

    // permute back in place (reads all completed before first barrier)
    for (int i = t; i < len; i += 256) {
        const ull rr = stage[i];
        const int key = ((int)((rr >> 17) & (RB - 1)) << 3) |
                        (int)(((unsigned)rr & 0x1FFFF) >> 14);
        const int p = atomicAdd(&cnt[key], 1);
        recs[s0 + p] = rr;
    }
}

// ---------------- P0: x -> fp16 ----------------
__global__ void tohalf_kernel(const float* __restrict__ x,
                              __half2* __restrict__ xh2, int n4)
{
    for (int i = blockIdx.x * blockDim.x + threadIdx.x; i < n4;
         i += gridDim.x * blockDim.x) {
        const float4 v = ((const float4*)x)[i];
        xh2[2 * i + 0] = __floats2half2_rn(v.x, v.y);
        xh2[2 * i + 1] = __floats2half2_rn(v.z, v.w);
    }
}

// ---------------- K6h2: CSR SpMM, split-wave half2 gathers (round-3 verified 84us) -
// r3/r5 evidence: every K6 variant pins FETCH at ~162MB and L2-miss stream at
// 1.9-2.3 TB/s; r3's serial-batch h2 is the fastest -> near the random-access
// L2-miss service ceiling. Kept byte-identical to round 3.
__global__ __launch_bounds__(256, 8) void spmm_csr_half2_kernel(
    const __half* __restrict__ xh,
    const int*   __restrict__ offsets_row,
    const int*   __restrict__ binbase,
    const ull*   __restrict__ recs,
    const int*   __restrict__ flags,
    float*       __restrict__ out,
    int n_nodes)
{
    const int row  = blockIdx.x * 4 + (threadIdx.x >> 6);
    if (row >= n_nodes) return;
    const int lane = threadIdx.x & 63;
    const int b    = row >> 7;

    if (__builtin_expect(flags[b], 0)) {
        // overflow path: unsorted bin-grouped records, full-wave scalar
        float acc = 0.f;
        const int s  = binbase[b];
        const int e  = binbase[b + 1];
        const int lr = row & (RB - 1);
        for (int j = s; j < e; ++j) {
            const ull rec = recs[j];
            if ((int)((rec >> 17) & (RB - 1)) == lr) {
                const int   c = (int)((unsigned)rec & 0x1FFFF);
                const float v = __uint_as_float((unsigned)(rec >> 32));
                acc += v * __half2float(xh[(size_t)c * D + lane]);
            }
        }
        out[(size_t)row * D + lane] = acc;
        return;
    }

    const __half2* xh2 = (const __half2*)xh;
    const int half = lane >> 5;
    const int fl   = lane & 31;

    const int s = offsets_row[row];
    const int e = offsets_row[row + 1];
    float accx = 0.f, accy = 0.f;

    int j = s;
    // full batches: 16 records, 8 gathers in flight
    for (; j + 16 <= e; j += 16) {
        float vv[8]; int aa[8];
        #pragma unroll
        for (int k = 0; k < 8; ++k) {
            const ull rec = recs[j + 2 * k + half];
            vv[k] = __uint_as_float((unsigned)(rec >> 32));
            aa[k] = ((int)((unsigned)rec & 0x1FFFF) << 5) + fl;
        }
        __half2 hv[8];
        #pragma unroll
        for (int k = 0; k < 8; ++k) hv[k] = xh2[aa[k]];   // 8 gathers = 16 recs ISSUED
        __builtin_amdgcn_sched_barrier(0);                // ...kept in flight
        #pragma unroll
        for (int k = 0; k < 8; ++k) {
            const float2 xf = __half22float2(hv[k]);
            accx = fmaf(vv[k], xf.x, accx);
            accy = fmaf(vv[k], xf.y, accy);
        }
    }
    // single masked batch for the tail: pipeline stays 8-deep
    if (j < e) {
        const int safe = e - 1;
        float vv[8]; int aa[8];
        #pragma unroll
        for (int k = 0; k < 8; ++k) {
            const int  idx = j + 2 * k + half;
            const bool ok  = idx < e;
            const ull  rec = recs[ok ? idx : safe];
            vv[k] = ok ? __uint_as_float((unsigned)(rec >> 32)) : 0.f;
            aa[k] = ((int)((unsigned)rec & 0x1FFFF) << 5) + fl;
        }
        __half2 hv[8];
        #pragma unroll
        for (int k = 0; k < 8; ++k) hv[k] = xh2[aa[k]];
        __builtin_amdgcn_sched_barrier(0);
        #pragma unroll
        for (int k = 0; k < 8; ++k) {
            const float2 xf = __half22float2(hv[k]);
            accx = fmaf(vv[k], xf.x, accx);
            accy = fmaf(vv[k], xf.y, accy);
        }
    }

    accx += __shfl_xor(accx, 32);
    accy += __shfl_xor(accy, 32);
    if (half == 0) {
        float2 o; o.x = accx; o.y = accy;
        ((float2*)out)[(size_t)row * 32 + fl] = o;
    }
}

static inline size_t align16(size_t v) { return (v + 15) & ~(size_t)15; }

extern "C" void kernel_launch(void* const* d_in, const int* in_sizes, int n_in,
                              void* d_out, int out_size, void* d_ws, size_t ws_size,
                              hipStream_t stream)
{
    // setup_inputs order: t, x, edge_row, edge_col, edge_val
    const float* x        = (const float*)d_in[1];
    const int*   edge_row = (const int*)d_in[2];
    const int*   edge_col = (const int*)d_in[3];
    const float* edge_val = (const float*)d_in[4];
    float*       out      = (float*)d_out;

    const int n_edges = in_sizes[2];
    const int n_nodes = out_size / D;
    const int nb      = (n_nodes + RB - 1) / RB;
    const int chunk   = (((n_edges + NBLK1 - 1) / NBLK1) + 3) & ~3;  // x4 for int4

    // workspace carve
    const size_t off_recs    = 0;                                               // n_edges*8
    const size_t off_xh      = align16(off_recs + (size_t)n_edges * 8);         // n_nodes*128
    const size_t off_counts  = align16(off_xh + (size_t)n_nodes * D * 2);       // nb*NBLK1 u16
    const size_t off_dest    = align16(off_counts + (size_t)nb * NBLK1 * 2);    // nb*NBLK1 int
    const size_t off_binsum  = align16(off_dest + (size_t)nb * NBLK1 * 4);      // nb ints
    const size_t off_binbase = align16(off_binsum + (size_t)nb * 4);            // nb+1 ints
    const size_t off_rowoffs = align16(off_binbase + (size_t)(nb + 1) * 4);     // n_nodes+1 ints
    const size_t off_flags   = align16(off_rowoffs + (size_t)(n_nodes + 1) * 4);// nb ints
    const size_t ws_needed   = off_flags + (size_t)nb * 4;

    if (ws_size < ws_needed || nb > NB_MAX || n_nodes > (1 << 17) ||
        chunk > P1CAP || n_edges < 1) {
        hipMemsetAsync(out, 0, (size_t)out_size * sizeof(float), stream);
        const int n_blocks = (n_edges + 3) / 4;
        spmm_atomic_kernel<<<n_blocks, 256, 0, stream>>>(
            x, edge_row, edge_col, edge_val, out, n_edges);
        return;
    }

    char* ws = (char*)d_ws;
    ull*    recs        = (ull*)(ws + off_recs);
    __half* xh          = (__half*)(ws + off_xh);
    u16*    counts      = (u16*)(ws + off_counts);
    int*    dest32      = (int*)(ws + off_dest);
    int*    binsum      = (int*)(ws + off_binsum);
    int*    binbase     = (int*)(ws + off_binbase);
    int*    offsets_row = (int*)(ws + off_rowoffs);
    int*    flags       = (int*)(ws + off_flags);

    // P1a: per-block row histogram
    p1a_hist_kernel<<<NBLK1, 256, 0, stream>>>(
        edge_row, counts, n_edges, nb, chunk);
    // P2': per-bin scan over blocks -> dest32, binsum
    p2_scanblocks_kernel<<<nb, 256, 0, stream>>>(counts, dest32, binsum, nb);
    // P3: bin bases + flag zeroing
    p3_scanbins_kernel<<<1, 1024, 0, stream>>>(binsum, binbase, flags, nb);
    // P1b: LDS counting sort + direct write to final bin regions
    p1b_sortwrite_kernel<<<NBLK1, 256, 0, stream>>>(
        edge_row, edge_col, edge_val, counts, dest32, binbase,
        recs, n_edges, nb, chunk);
    // P4': per-bin in-place sort by (localrow | colslice) + row offsets
    p4_sortbin_kernel<<<nb, 256, 0, stream>>>(
        binbase, recs, offsets_row, flags, n_nodes);
    // P0: x -> fp16
    const int n4 = (n_nodes * D) / 4;
    tohalf_kernel<<<2048, 256, 0, stream>>>(x, (__half2*)xh, n4);
    // K6h2: CSR SpMM (round-3 verified)
    spmm_csr_half2_kernel<<<(n_nodes + 3) / 4, 256, 0, stream>>>(
        xh, offsets_row, binbase, recs, flags, out, n_nodes);
}